// Round 4
// baseline (846.631 us; speedup 1.0000x reference)
//
#include <hip/hip_runtime.h>

// B=2, S=2048, D=1024, H=16, Khid=64.  Inputs/outputs f32; MFMA compute bf16.
typedef unsigned short u16;
typedef unsigned int u32;
typedef unsigned long long u64;
typedef __attribute__((ext_vector_type(8))) short short8;   // 8 bf16 (4 VGPRs)
typedef __attribute__((ext_vector_type(8))) float float8;   // 32B
typedef __attribute__((ext_vector_type(4))) float floatx4;  // MFMA accumulator

__device__ __forceinline__ u16 f2bf(float f) {
    unsigned u = __float_as_uint(f);
    return (u16)((u + 0x7FFFu + ((u >> 16) & 1u)) >> 16);  // RNE
}

#define MFMA(a, b, c) __builtin_amdgcn_mfma_f32_16x16x32_bf16((a), (b), (c), 0, 0, 0)

// Padded LDS strides (u16 units): wave64 b128 ops at the 8-bank-pass floor.
#define AST 40
#define KST 72
#define C2 0.18033688011112043f   // 0.125 * log2(e): softmax in exp2 domain (no max
                                  // subtraction: scores ~N(0,1), overflow needs s>700)

// ---------------------------------------------------------------------------
// Weight pre-transpose (one launch): slots 0..2 = W_Q/K/V [16][1024][64] f32
// -> wt3[slot][h][n][1024d] bf16; slot 3 = W_proj [1024][1024] -> wpT[n][c] bf16.
// grid (2048) x 256
__global__ __launch_bounds__(256) void k_wtall(
    const float* __restrict__ wq, const float* __restrict__ wk,
    const float* __restrict__ wv, const float* __restrict__ wp,
    u16* __restrict__ wt3, u16* __restrict__ wpT)
{
    int slot = blockIdx.x >> 9;
    int id = (blockIdx.x & 511) * 256 + threadIdx.x;
    const float* in; u16* out; int logC;
    if (slot == 3) { in = wp; out = wpT; logC = 10; }
    else {
        in = (slot == 0) ? wq : (slot == 1 ? wk : wv);
        out = wt3 + (size_t)slot * 1048576;
        logC = 6;
    }
    int rg = id & 127;
    int rest = id >> 7;
    int C = 1 << logC;
    int cc = rest & (C - 1);
    int bt = rest >> logC;
    const float* src = in + ((size_t)bt << (10 + logC)) + cc;
    int r0 = rg * 8;
    short8 o;
    #pragma unroll
    for (int j = 0; j < 8; j++) o[j] = (short)f2bf(src[(size_t)(r0 + j) << logC]);
    *(short8*)&out[(((size_t)bt << logC) + cc) * 1024 + r0] = o;
}

// ---------------------------------------------------------------------------
// Merged Q+K+V projection, 8 waves, 128-row tiles, BK=64.
// Q,K -> [bh][s][64] bf16; V^T -> [bh][n][2048] bf16.  grid (32, 16) x 512
__global__ __launch_bounds__(512, 4) void k_projqkv(
    const float* __restrict__ x,
    const float* __restrict__ wq, const float* __restrict__ bq,
    const float* __restrict__ wk, const float* __restrict__ bk,
    const float* __restrict__ wv, const float* __restrict__ bv,
    const u16* __restrict__ wtT,          // [3][16][64][1024] bf16 or null
    u16* __restrict__ Qout, u16* __restrict__ Kout, u16* __restrict__ Vout)
{
    int mt = blockIdx.x, h = blockIdx.y;
    int tid = threadIdx.x, wave = tid >> 6, lane = tid & 63;
    int col = lane & 15, quad = lane >> 4, m0 = wave * 16;
    int rg0 = mt * 128;
    bool doQ = (Qout != nullptr);

    __shared__ __align__(16) char pool[(128 + 3 * 64) * KST * 2];   // 46080B
    u16* As = (u16*)pool;           // [128 s][KST]
    u16* Bq = As + 128 * KST;       // [64 n][KST]
    u16* Bk = Bq + 64 * KST;
    u16* Bv = Bk + 64 * KST;

    floatx4 aQ[4], aK[4], aV[4];
    for (int i = 0; i < 4; i++) { aQ[i] = (floatx4){0,0,0,0}; aK[i] = (floatx4){0,0,0,0}; aV[i] = (floatx4){0,0,0,0}; }

    int ar = tid >> 2, ac = (tid & 3) * 16;   // A staging: 128 s x 64 d
    float8 xa0 = *(const float8*)&x[(size_t)(rg0 + ar) * 1024 + ac];
    float8 xa1 = *(const float8*)&x[(size_t)(rg0 + ar) * 1024 + ac + 8];

    if (wtT) {
        const u16* wqT = wtT + (size_t)h * 65536;
        const u16* wkT = wqT + 1048576;
        const u16* wvT = wkT + 1048576;
        int br = tid >> 3, bc = (tid & 7) * 8;   // B staging: 64 n x 64 d
        short8 q8 = *(const short8*)&wqT[(size_t)br * 1024 + bc];
        short8 k8 = *(const short8*)&wkT[(size_t)br * 1024 + bc];
        short8 v8 = *(const short8*)&wvT[(size_t)br * 1024 + bc];
        for (int dk = 0; dk < 1024; dk += 64) {
            short8 a8;
            #pragma unroll
            for (int j = 0; j < 8; j++) a8[j] = (short)f2bf(xa0[j]);
            *(short8*)&As[ar * KST + ac] = a8;
            #pragma unroll
            for (int j = 0; j < 8; j++) a8[j] = (short)f2bf(xa1[j]);
            *(short8*)&As[ar * KST + ac + 8] = a8;
            *(short8*)&Bq[br * KST + bc] = q8;
            *(short8*)&Bk[br * KST + bc] = k8;
            *(short8*)&Bv[br * KST + bc] = v8;
            __syncthreads();
            if (dk + 64 < 1024) {
                xa0 = *(const float8*)&x[(size_t)(rg0 + ar) * 1024 + dk + 64 + ac];
                xa1 = *(const float8*)&x[(size_t)(rg0 + ar) * 1024 + dk + 64 + ac + 8];
                q8 = *(const short8*)&wqT[(size_t)br * 1024 + dk + 64 + bc];
                k8 = *(const short8*)&wkT[(size_t)br * 1024 + dk + 64 + bc];
                v8 = *(const short8*)&wvT[(size_t)br * 1024 + dk + 64 + bc];
            }
            short8 a0 = *(const short8*)&As[(m0 + col) * KST + quad * 8];
            short8 a1 = *(const short8*)&As[(m0 + col) * KST + 32 + quad * 8];
            #pragma unroll
            for (int nt = 0; nt < 4; nt++) {
                int bn = nt * 16 + col;
                short8 fq0 = *(const short8*)&Bq[bn * KST + quad * 8];
                short8 fq1 = *(const short8*)&Bq[bn * KST + 32 + quad * 8];
                short8 fk0 = *(const short8*)&Bk[bn * KST + quad * 8];
                short8 fk1 = *(const short8*)&Bk[bn * KST + 32 + quad * 8];
                short8 fv0 = *(const short8*)&Bv[bn * KST + quad * 8];
                short8 fv1 = *(const short8*)&Bv[bn * KST + 32 + quad * 8];
                if (doQ) { aQ[nt] = MFMA(a0, fq0, aQ[nt]); aQ[nt] = MFMA(a1, fq1, aQ[nt]); }
                aK[nt] = MFMA(a0, fk0, aK[nt]); aK[nt] = MFMA(a1, fk1, aK[nt]);
                aV[nt] = MFMA(a0, fv0, aV[nt]); aV[nt] = MFMA(a1, fv1, aV[nt]);
            }
            __syncthreads();
        }
    } else {
        // f32-weight fallback: transpose staging
        int dr = tid >> 3, nc = (tid & 7) * 8;   // 64 d x 64 n
        const float* whq = wq + (size_t)h * 65536;
        const float* whk = wk + (size_t)h * 65536;
        const float* whv = wv + (size_t)h * 65536;
        float8 qp = *(const float8*)&whq[(size_t)dr * 64 + nc];
        float8 kp = *(const float8*)&whk[(size_t)dr * 64 + nc];
        float8 vp = *(const float8*)&whv[(size_t)dr * 64 + nc];
        for (int dk = 0; dk < 1024; dk += 64) {
            short8 a8;
            #pragma unroll
            for (int j = 0; j < 8; j++) a8[j] = (short)f2bf(xa0[j]);
            *(short8*)&As[ar * KST + ac] = a8;
            #pragma unroll
            for (int j = 0; j < 8; j++) a8[j] = (short)f2bf(xa1[j]);
            *(short8*)&As[ar * KST + ac + 8] = a8;
            #pragma unroll
            for (int j = 0; j < 8; j++) Bk[(nc + j) * KST + dr] = f2bf(kp[j]);
            #pragma unroll
            for (int j = 0; j < 8; j++) Bv[(nc + j) * KST + dr] = f2bf(vp[j]);
            if (doQ) {
                #pragma unroll
                for (int j = 0; j < 8; j++) Bq[(nc + j) * KST + dr] = f2bf(qp[j]);
            }
            __syncthreads();
            if (dk + 64 < 1024) {
                xa0 = *(const float8*)&x[(size_t)(rg0 + ar) * 1024 + dk + 64 + ac];
                xa1 = *(const float8*)&x[(size_t)(rg0 + ar) * 1024 + dk + 64 + ac + 8];
                qp = *(const float8*)&whq[(size_t)(dk + 64 + dr) * 64 + nc];
                kp = *(const float8*)&whk[(size_t)(dk + 64 + dr) * 64 + nc];
                vp = *(const float8*)&whv[(size_t)(dk + 64 + dr) * 64 + nc];
            }
            short8 a0 = *(const short8*)&As[(m0 + col) * KST + quad * 8];
            short8 a1 = *(const short8*)&As[(m0 + col) * KST + 32 + quad * 8];
            #pragma unroll
            for (int nt = 0; nt < 4; nt++) {
                int bn = nt * 16 + col;
                short8 fk0 = *(const short8*)&Bk[bn * KST + quad * 8];
                short8 fk1 = *(const short8*)&Bk[bn * KST + 32 + quad * 8];
                short8 fv0 = *(const short8*)&Bv[bn * KST + quad * 8];
                short8 fv1 = *(const short8*)&Bv[bn * KST + 32 + quad * 8];
                aK[nt] = MFMA(a0, fk0, aK[nt]); aK[nt] = MFMA(a1, fk1, aK[nt]);
                aV[nt] = MFMA(a0, fv0, aV[nt]); aV[nt] = MFMA(a1, fv1, aV[nt]);
                if (doQ) {
                    short8 fq0 = *(const short8*)&Bq[bn * KST + quad * 8];
                    short8 fq1 = *(const short8*)&Bq[bn * KST + 32 + quad * 8];
                    aQ[nt] = MFMA(a0, fq0, aQ[nt]); aQ[nt] = MFMA(a1, fq1, aQ[nt]);
                }
            }
            __syncthreads();
        }
    }

    int bb = rg0 >> 11, s0b = rg0 & 2047;
    size_t bh = (size_t)(bb * 16 + h);

    #pragma unroll
    for (int nt = 0; nt < 4; nt++) {
        int n = nt * 16 + col;
        float bkl = bk[h * 64 + n];
        #pragma unroll
        for (int r = 0; r < 4; r++) {
            int rowl = m0 + quad * 4 + r;
            Kout[(bh * 2048 + s0b + rowl) * 64 + n] = f2bf(aK[nt][r] + bkl);
        }
    }
    if (doQ) {
        #pragma unroll
        for (int nt = 0; nt < 4; nt++) {
            int n = nt * 16 + col;
            float bql = bq[h * 64 + n];
            #pragma unroll
            for (int r = 0; r < 4; r++) {
                int rowl = m0 + quad * 4 + r;
                Qout[(bh * 2048 + s0b + rowl) * 64 + n] = f2bf(aQ[nt][r] + bql);
            }
        }
    }
    // V: LDS transpose -> coalesced 32B/lane rows.  VT [64 n][stride 136]
    u16* VT = (u16*)pool;   // 17408B, fits in As region (18432B)
    #pragma unroll
    for (int nt = 0; nt < 4; nt++) {
        int n = nt * 16 + col;
        float bvl = bv[h * 64 + n];
        #pragma unroll
        for (int r = 0; r < 4; r++) {
            int rowl = m0 + quad * 4 + r;
            VT[n * 136 + rowl] = f2bf(aV[nt][r] + bvl);
        }
    }
    __syncthreads();
    {
        int n2 = tid >> 3, sseg = (tid & 7) * 16;
        short8 p0 = *(const short8*)&VT[n2 * 136 + sseg];
        short8 p1 = *(const short8*)&VT[n2 * 136 + sseg + 8];
        u16* dst = &Vout[(bh * 64 + n2) * 2048 + s0b + sseg];
        *(short8*)dst = p0;
        *(short8*)(dst + 8) = p1;
    }
}

// ---------------------------------------------------------------------------
// Pack mask [2,2048,2048] i32 -> transposed bitmask bits[(b*32+w)*2048+s].
__global__ __launch_bounds__(256) void k_pack(
    const int* __restrict__ mask, u64* __restrict__ bits)
{
    int row = blockIdx.x;              // b*2048 + s
    int b = row >> 11, s = row & 2047;
    int wv = threadIdx.x >> 6, lane = threadIdx.x & 63;
    for (int w = wv; w < 32; w += 4) {
        int m = mask[(size_t)row * 2048 + w * 64 + lane];
        u64 bal = __ballot(m != 0);
        if (lane == 0) bits[((size_t)(b * 32 + w)) * 2048 + s] = bal;
    }
}

// ---------------------------------------------------------------------------
// Fused scores+softmax+PV.  8 waves, 128 s-rows per block (grid 16 x 32).
// No max subtraction (scores bounded): pass 1 = sum exp2 only (swapped QK^T,
// t lane-local, TBLK=128); pass 2 = recompute, p=exp2(s*C2)/l, nontemporal
// write p, bf16 P tile -> PV MFMA -> concat.
__global__ __launch_bounds__(512, 4) void k_fused(
    const float* __restrict__ x, const float* __restrict__ wq, const float* __restrict__ bq,
    const u16* __restrict__ Qbuf, const u16* __restrict__ Kbuf, const u16* __restrict__ Vt,
    const u64* __restrict__ mbits,
    float* __restrict__ sc, u16* __restrict__ concat)
{
    int st = blockIdx.x, bh = blockIdx.y;
    int b = bh >> 4, h = bh & 15;
    int s0 = st * 128;
    int tid = threadIdx.x, wave = tid >> 6, lane = tid & 63;
    int col = lane & 15, quad = lane >> 4, m0 = wave * 16;
    int qs4 = quad * 4;

    __shared__ __align__(16) char pool[(128 + 2 * 64) * KST * 2];   // 36864B
    u16* Ps = (u16*)pool;                        // Q tile / pass2 P tile [128][KST]
    u16* Ks = (u16*)(pool + 128 * KST * 2);      // pass2 K tile [64][KST]
    u16* Vs = Ks + 64 * KST;                     // pass2 V tile [64][KST]
    u16* K128 = Ks;                              // pass1 K tile [128][KST] (Ks+Vs)
    __shared__ u64 Mw[256];
    __shared__ float lrun[128];

    // ---- Q tile -> Ps ----
    if (Qbuf) {
        const u16* Qh = Qbuf + (size_t)bh * 2048 * 64;
        int qr = tid >> 2, qc = (tid & 3) * 16;
        *(short8*)&Ps[qr * KST + qc]     = *(const short8*)&Qh[(size_t)(s0 + qr) * 64 + qc];
        *(short8*)&Ps[qr * KST + qc + 8] = *(const short8*)&Qh[(size_t)(s0 + qr) * 64 + qc + 8];
        __syncthreads();
    } else {
        // fallback: compute Q on the fly (BK=32); As aliases Ps, Bs aliases Ks
        floatx4 acc[4];
        for (int i = 0; i < 4; i++) acc[i] = (floatx4){0,0,0,0};
        int lr = tid >> 2, lc = (tid & 3) * 8;     // 128 s x 32 d
        int dr = tid >> 4, nc = (tid & 15) * 4;    // 32 d x 64 n
        const float* wh = wq + (size_t)h * 65536;
        const float* xb = x + ((size_t)b * 2048 + s0) * 1024;
        u16* As = Ps; u16* Bs = Ks;
        for (int dk = 0; dk < 1024; dk += 32) {
            float8 av = *(const float8*)&xb[(size_t)lr * 1024 + dk + lc];
            short8 a8;
            #pragma unroll
            for (int j = 0; j < 8; j++) a8[j] = (short)f2bf(av[j]);
            *(short8*)&As[lr * AST + lc] = a8;
            #pragma unroll
            for (int j = 0; j < 4; j++) Bs[(nc + j) * AST + dr] = f2bf(wh[(size_t)(dk + dr) * 64 + nc + j]);
            __syncthreads();
            short8 a = *(const short8*)&As[(m0 + col) * AST + quad * 8];
            #pragma unroll
            for (int nt = 0; nt < 4; nt++) {
                short8 b2 = *(const short8*)&Bs[(nt * 16 + col) * AST + quad * 8];
                acc[nt] = MFMA(a, b2, acc[nt]);
            }
            __syncthreads();
        }
        #pragma unroll
        for (int nt = 0; nt < 4; nt++) {
            int n = nt * 16 + col;
            float bvq = bq[h * 64 + n];
            #pragma unroll
            for (int r = 0; r < 4; r++) {
                int rowl = m0 + qs4 + r;
                Ps[rowl * KST + n] = f2bf(acc[nt][r] + bvq);
            }
        }
        __syncthreads();
    }
    short8 aq0 = *(const short8*)&Ps[(m0 + col) * KST + quad * 8];
    short8 aq1 = *(const short8*)&Ps[(m0 + col) * KST + 32 + quad * 8];

    const u16* Kh = Kbuf + (size_t)bh * 2048 * 64;
    const u16* Vh = Vt + (size_t)bh * 64 * 2048;
    const u64* mrow = mbits + (size_t)b * 65536;
    int srow = tid >> 3, soff = (tid & 7) * 8;

    // ---- Pass 1: l = sum exp2(score*C2), swapped QK^T, TBLK=128 ----
    float lreg = 0.f;   // for s-row = m0 + col
    {
        short8 ka = *(const short8*)&Kh[(size_t)srow * 64 + soff];
        short8 kb = *(const short8*)&Kh[(size_t)(srow + 64) * 64 + soff];
        for (int t0 = 0; t0 < 2048; t0 += 128) {
            *(short8*)&K128[srow * KST + soff]        = ka;
            *(short8*)&K128[(srow + 64) * KST + soff] = kb;
            if (tid < 256) Mw[tid] = mrow[(size_t)((t0 >> 6) + (tid >> 7)) * 2048 + s0 + (tid & 127)];
            __syncthreads();
            if (t0 + 128 < 2048) {
                ka = *(const short8*)&Kh[(size_t)(t0 + 128 + srow) * 64 + soff];
                kb = *(const short8*)&Kh[(size_t)(t0 + 192 + srow) * 64 + soff];
            }
            #pragma unroll
            for (int half = 0; half < 2; half++) {
                floatx4 c4[4];
                #pragma unroll
                for (int tt = 0; tt < 4; tt++) {
                    c4[tt] = (floatx4){0,0,0,0};
                    int trow = (half * 4 + tt) * 16 + col;
                    short8 f0 = *(const short8*)&K128[trow * KST + quad * 8];
                    short8 f1 = *(const short8*)&K128[trow * KST + 32 + quad * 8];
                    c4[tt] = MFMA(f0, aq0, c4[tt]);   // D[t][s]: t lane-local
                    c4[tt] = MFMA(f1, aq1, c4[tt]);
                }
                u64 w = Mw[half * 128 + m0 + col];
                u32 blo = ((u32)w) >> qs4;
                u32 bhi = ((u32)(w >> 32)) >> qs4;
                float ss = 0.f;
                #pragma unroll
                for (int tt = 0; tt < 4; tt++) {
                    u32 bsel = (tt < 2) ? blo : bhi;
                    #pragma unroll
                    for (int r = 0; r < 4; r++) {
                        bool on = (bsel >> ((tt & 1) * 16 + r)) & 1u;
                        ss += exp2f(on ? c4[tt][r] * C2 : -1e30f);   // masked -> +0
                    }
                }
                lreg += ss;
            }
            __syncthreads();
        }
    }
    lreg += __shfl_xor(lreg, 16, 64);
    lreg += __shfl_xor(lreg, 32, 64);
    if (quad == 0) lrun[m0 + col] = lreg;
    __syncthreads();

    // ---- Pass 2: recompute (normal orientation), p = exp2(s*C2)/l, PV ----
    float rl4[4];
    #pragma unroll
    for (int r = 0; r < 4; r++) {
        float l = lrun[m0 + qs4 + r];
        rl4[r] = (l > 0.f) ? 1.0f / l : 0.f;
    }
    floatx4 accp[4];
    for (int i = 0; i < 4; i++) accp[i] = (floatx4){0,0,0,0};
    float* scb = sc + (size_t)bh * 4194304;
    {
        short8 kp = *(const short8*)&Kh[(size_t)srow * 64 + soff];
        short8 vp = *(const short8*)&Vh[(size_t)srow * 2048 + soff];
        for (int t0 = 0; t0 < 2048; t0 += 64) {
            *(short8*)&Ks[srow * KST + soff] = kp;
            *(short8*)&Vs[srow * KST + soff] = vp;
            if (tid < 128) Mw[tid] = mrow[(size_t)(t0 >> 6) * 2048 + s0 + tid];
            __syncthreads();
            if (t0 + 64 < 2048) {
                kp = *(const short8*)&Kh[(size_t)(t0 + 64 + srow) * 64 + soff];
                vp = *(const short8*)&Vh[(size_t)srow * 2048 + t0 + 64 + soff];
            }
            floatx4 c4[4];
            #pragma unroll
            for (int nt = 0; nt < 4; nt++) {
                c4[nt] = (floatx4){0,0,0,0};
                short8 f0 = *(const short8*)&Ks[(nt * 16 + col) * KST + quad * 8];
                short8 f1 = *(const short8*)&Ks[(nt * 16 + col) * KST + 32 + quad * 8];
                c4[nt] = MFMA(aq0, f0, c4[nt]);
                c4[nt] = MFMA(aq1, f1, c4[nt]);
            }
            #pragma unroll
            for (int r = 0; r < 4; r++) {
                int rowl = m0 + qs4 + r;
                u64 w = Mw[rowl];
                u32 blo = ((u32)w) >> col;
                u32 bhi = ((u32)(w >> 32)) >> col;
                size_t base = (size_t)(s0 + rowl) * 2048 + t0;
                #pragma unroll
                for (int nt = 0; nt < 4; nt++) {
                    bool on = ((nt < 2 ? blo : bhi) >> ((nt & 1) * 16)) & 1u;
                    float p = exp2f(on ? c4[nt][r] * C2 : -1e30f) * rl4[r];
                    __builtin_nontemporal_store(p, &scb[base + nt * 16 + col]);
                    Ps[rowl * KST + nt * 16 + col] = f2bf(p);
                }
            }
            __syncthreads();
            short8 ap0 = *(const short8*)&Ps[(m0 + col) * KST + quad * 8];
            short8 ap1 = *(const short8*)&Ps[(m0 + col) * KST + 32 + quad * 8];
            #pragma unroll
            for (int nt = 0; nt < 4; nt++) {
                short8 f0 = *(const short8*)&Vs[(nt * 16 + col) * KST + quad * 8];
                short8 f1 = *(const short8*)&Vs[(nt * 16 + col) * KST + 32 + quad * 8];
                accp[nt] = MFMA(ap0, f0, accp[nt]);
                accp[nt] = MFMA(ap1, f1, accp[nt]);
            }
            __syncthreads();
        }
    }
    #pragma unroll
    for (int nt = 0; nt < 4; nt++) {
        int n = nt * 16 + col;
        #pragma unroll
        for (int r = 0; r < 4; r++) {
            int rowl = m0 + qs4 + r;
            concat[((size_t)(b * 2048 + s0 + rowl)) * 1024 + h * 64 + n] = f2bf(accp[nt][r]);
        }
    }
}

// ---------------------------------------------------------------------------
// Output projection: out f32 = concat(bf16) @ W_proj + b_proj.  BK=64.
// grid (64,16) x 256
__global__ __launch_bounds__(256) void k_out(
    const u16* __restrict__ concat, const float* __restrict__ wp,
    const u16* __restrict__ wpT, const float* __restrict__ bp,
    float* __restrict__ outp)
{
    int mt = blockIdx.x, ntile = blockIdx.y;
    int n0 = ntile * 64;
    int tid = threadIdx.x, wave = tid >> 6, lane = tid & 63;
    int col = lane & 15, quad = lane >> 4, m0 = wave * 16;
    int rg0 = mt * 64;

    __shared__ u16 As[64 * KST];
    __shared__ u16 Bs[64 * KST];

    floatx4 acc[4];
    for (int i = 0; i < 4; i++) acc[i] = (floatx4){0,0,0,0};

    int ar = tid >> 2, ac = (tid & 3) * 16;
    short8 ap0 = *(const short8*)&concat[(size_t)(rg0 + ar) * 1024 + ac];
    short8 ap1 = *(const short8*)&concat[(size_t)(rg0 + ar) * 1024 + ac + 8];
    if (wpT) {
        int nr = tid >> 2, dc = (tid & 3) * 16;
        short8 w0 = *(const short8*)&wpT[(size_t)(n0 + nr) * 1024 + dc];
        short8 w1 = *(const short8*)&wpT[(size_t)(n0 + nr) * 1024 + dc + 8];
        for (int c = 0; c < 1024; c += 64) {
            *(short8*)&As[ar * KST + ac]     = ap0;
            *(short8*)&As[ar * KST + ac + 8] = ap1;
            *(short8*)&Bs[nr * KST + dc]     = w0;
            *(short8*)&Bs[nr * KST + dc + 8] = w1;
            __syncthreads();
            if (c + 64 < 1024) {
                ap0 = *(const short8*)&concat[(size_t)(rg0 + ar) * 1024 + c + 64 + ac];
                ap1 = *(const short8*)&concat[(size_t)(rg0 + ar) * 1024 + c + 64 + ac + 8];
                w0 = *(const short8*)&wpT[(size_t)(n0 + nr) * 1024 + c + 64 + dc];
                w1 = *(const short8*)&wpT[(size_t)(n0 + nr) * 1024 + c + 64 + dc + 8];
            }
            short8 a0 = *(const short8*)&As[(m0 + col) * KST + quad * 8];
            short8 a1 = *(const short8*)&As[(m0 + col) * KST + 32 + quad * 8];
            #pragma unroll
            for (int nt = 0; nt < 4; nt++) {
                short8 f0 = *(const short8*)&Bs[(nt * 16 + col) * KST + quad * 8];
                short8 f1 = *(const short8*)&Bs[(nt * 16 + col) * KST + 32 + quad * 8];
                acc[nt] = MFMA(a0, f0, acc[nt]);
                acc[nt] = MFMA(a1, f1, acc[nt]);
            }
            __syncthreads();
        }
    } else {
        int cr = tid >> 2, nc = (tid & 3) * 16;
        float8 f0 = *(const float8*)&wp[(size_t)cr * 1024 + n0 + nc];
        float8 f1 = *(const float8*)&wp[(size_t)cr * 1024 + n0 + nc + 8];
        for (int c = 0; c < 1024; c += 64) {
            *(short8*)&As[ar * KST + ac]     = ap0;
            *(short8*)&As[ar * KST + ac + 8] = ap1;
            #pragma unroll
            for (int j = 0; j < 8; j++) Bs[(nc + j) * KST + cr] = f2bf(f0[j]);
            #pragma unroll
            for (int j = 0; j < 8; j++) Bs[(nc + 8 + j) * KST + cr] = f2bf(f1[j]);
            __syncthreads();
            if (c + 64 < 1024) {
                ap0 = *(const short8*)&concat[(size_t)(rg0 + ar) * 1024 + c + 64 + ac];
                ap1 = *(const short8*)&concat[(size_t)(rg0 + ar) * 1024 + c + 64 + ac + 8];
                f0 = *(const float8*)&wp[(size_t)(c + 64 + cr) * 1024 + n0 + nc];
                f1 = *(const float8*)&wp[(size_t)(c + 64 + cr) * 1024 + n0 + nc + 8];
            }
            short8 a0 = *(const short8*)&As[(m0 + col) * KST + quad * 8];
            short8 a1 = *(const short8*)&As[(m0 + col) * KST + 32 + quad * 8];
            #pragma unroll
            for (int nt = 0; nt < 4; nt++) {
                short8 g0 = *(const short8*)&Bs[(nt * 16 + col) * KST + quad * 8];
                short8 g1 = *(const short8*)&Bs[(nt * 16 + col) * KST + 32 + quad * 8];
                acc[nt] = MFMA(a0, g0, acc[nt]);
                acc[nt] = MFMA(a1, g1, acc[nt]);
            }
            __syncthreads();
        }
    }
    #pragma unroll
    for (int nt = 0; nt < 4; nt++) {
        int n = n0 + nt * 16 + col;
        float bv = bp[n];
        #pragma unroll
        for (int r = 0; r < 4; r++) {
            int rowl = m0 + quad * 4 + r;
            __builtin_nontemporal_store(acc[nt][r] + bv, &outp[(size_t)(rg0 + rowl) * 1024 + n]);
        }
    }
}

// ---------------------------------------------------------------------------
extern "C" void kernel_launch(void* const* d_in, const int* in_sizes, int n_in,
                              void* d_out, int out_size, void* d_ws, size_t ws_size,
                              hipStream_t stream) {
    const float* x  = (const float*)d_in[0];
    const float* WQ = (const float*)d_in[1];
    const float* bQ = (const float*)d_in[2];
    const float* WK = (const float*)d_in[3];
    const float* bK = (const float*)d_in[4];
    const float* WV = (const float*)d_in[5];
    const float* bV = (const float*)d_in[6];
    const float* WP = (const float*)d_in[7];
    const float* bP = (const float*)d_in[8];
    const int* mask = (const int*)d_in[9];

    float* out = (float*)d_out;
    float* attn_out = out;                     // [2,2048,1024] f32
    float* sc = out + (size_t)4194304;         // [2,16,2048,2048] f32

    const size_t NEED_BIG = (size_t)4 * 8388608 + 1048576 + 6291456 + 2097152; // 42.99MB
    const size_t NEED_MID = (size_t)3 * 8388608 + 1048576;                     // 26.2MB
    u16 *Kbuf, *Vtb, *Qbuf = nullptr, *concat, *wt3 = nullptr, *wpT = nullptr;
    u64* mbits;
    if (ws_size >= NEED_BIG) {
        char* ws = (char*)d_ws;
        Kbuf   = (u16*)ws;   ws += 8388608;
        Vtb    = (u16*)ws;   ws += 8388608;
        Qbuf   = (u16*)ws;   ws += 8388608;
        concat = (u16*)ws;   ws += 8388608;
        mbits  = (u64*)ws;   ws += 1048576;
        wt3    = (u16*)ws;   ws += 6291456;
        wpT    = (u16*)ws;
    } else if (ws_size >= NEED_MID) {
        char* ws = (char*)d_ws;
        Kbuf   = (u16*)ws;   ws += 8388608;
        Vtb    = (u16*)ws;   ws += 8388608;
        concat = (u16*)ws;   ws += 8388608;
        mbits  = (u64*)ws;
    } else {
        // Fallback: K|Vt overlay dead attn_out; mbits in dead W_K (packed
        // after k_projqkv reads W_K); concat in dead mask (after k_pack).
        Kbuf   = (u16*)attn_out;
        Vtb    = Kbuf + (size_t)4194304;
        mbits  = (u64*)d_in[3];
        concat = (u16*)d_in[9];
    }

    if (wt3)
        k_wtall<<<dim3(2048), 256, 0, stream>>>(WQ, WK, WV, WP, wt3, wpT);
    k_projqkv<<<dim3(32, 16), 512, 0, stream>>>(x, WQ, bQ, WK, bK, WV, bV,
                                                wt3, Qbuf, Kbuf, Vtb);
    k_pack<<<dim3(4096), 256, 0, stream>>>(mask, mbits);
    k_fused<<<dim3(16, 32), 512, 0, stream>>>(x, WQ, bQ, Qbuf, Kbuf, Vtb, mbits, sc, concat);
    k_out<<<dim3(64, 16), 256, 0, stream>>>(concat, WP, wpT, bP, attn_out);
}